// Round 1
// baseline (161.801 us; speedup 1.0000x reference)
//
#include <hip/hip_runtime.h>

// PZCell: y_t = b0*x_t + b1*x_{t-1} + b2*x_{t-2} - a1*y_{t-1} - a2*y_{t-2}
// (den = pole_coeffs[0] == 1 always; real-state cast makes only Re(coeffs) matter)
//
// Parallelization: each row (4096) split into 32 chunks of 64 steps. Chunks
// warm up from zero state starting 512 steps early (pole radius 0.95 ->
// 0.95^512 ~ 4e-12 residual). Chunks whose warmup window hits t=0 are exact.

#define T_LEN   2048
#define B_ROWS  4096
#define CHUNK   64
#define NCHUNK  (T_LEN / CHUNK)   // 32
#define WARM    512

__global__ __launch_bounds__(256) void pzcell_kernel(
    const float* __restrict__ x,
    const float* __restrict__ gain_ri,
    const float* __restrict__ poles_ri,
    const float* __restrict__ zeros_ri,
    float* __restrict__ out)
{
    // ---- coefficients (identical on every thread; tiny) ----
    float gr = gain_ri[0], gi = gain_ri[1];
    float p1r = poles_ri[0], p1i = poles_ri[1];
    float p2r = poles_ri[2], p2i = poles_ri[3];
    float z1r = zeros_ri[0], z1i = zeros_ri[1];
    float z2r = zeros_ri[2], z2i = zeros_ri[3];

    // pole_coeffs = [1, -(p1+p2), p1*p2]; only real parts multiply the real state
    float a1 = -(p1r + p2r);
    float a2 = p1r * p2r - p1i * p2i;
    // zero_coeffs = [1, -(z1+z2), z1*z2]; b_k = Re(gain * zc_k)
    float zc1r = -(z1r + z2r), zc1i = -(z1i + z2i);
    float zc2r = z1r * z2r - z1i * z2i;
    float zc2i = z1r * z2i + z1i * z2r;
    float b0 = gr;
    float b1 = gr * zc1r - gi * zc1i;
    float b2 = gr * zc2r - gi * zc2i;

    int tid   = blockIdx.x * blockDim.x + threadIdx.x;
    int chunk = tid & (NCHUNK - 1);
    int row   = tid >> 5;            // NCHUNK == 32
    if (row >= B_ROWS) return;

    int tstart = chunk * CHUNK;          // first emitted step
    int t0 = tstart - WARM;              // warmup start
    if (t0 < 0) t0 = 0;                  // exact from true t=0
    int nsteps = tstart + CHUNK - t0;    // multiple of 4

    const float4* __restrict__ xv =
        (const float4*)(x + (size_t)row * T_LEN + t0);
    float4* __restrict__ yv =
        (float4*)(out + (size_t)row * T_LEN + tstart);

    int ngroups = nsteps >> 2;
    int g_emit  = (tstart - t0) >> 2;    // groups before this are warmup-only

    float x1 = 0.f, x2 = 0.f, y1 = 0.f, y2 = 0.f;

    for (int g = 0; g < ngroups; ++g) {
        float4 xi = xv[g];
        float4 yo;
        float f, y;

        f = b0 * xi.x + b1 * x1 + b2 * x2;
        y = f - a1 * y1 - a2 * y2;
        yo.x = y; x2 = x1; x1 = xi.x; y2 = y1; y1 = y;

        f = b0 * xi.y + b1 * x1 + b2 * x2;
        y = f - a1 * y1 - a2 * y2;
        yo.y = y; x2 = x1; x1 = xi.y; y2 = y1; y1 = y;

        f = b0 * xi.z + b1 * x1 + b2 * x2;
        y = f - a1 * y1 - a2 * y2;
        yo.z = y; x2 = x1; x1 = xi.z; y2 = y1; y1 = y;

        f = b0 * xi.w + b1 * x1 + b2 * x2;
        y = f - a1 * y1 - a2 * y2;
        yo.w = y; x2 = x1; x1 = xi.w; y2 = y1; y1 = y;

        if (g >= g_emit) {
            yv[g - g_emit] = yo;
        }
    }
}

extern "C" void kernel_launch(void* const* d_in, const int* in_sizes, int n_in,
                              void* d_out, int out_size, void* d_ws, size_t ws_size,
                              hipStream_t stream) {
    const float* x        = (const float*)d_in[0];
    const float* gain_ri  = (const float*)d_in[1];
    const float* poles_ri = (const float*)d_in[2];
    const float* zeros_ri = (const float*)d_in[3];
    float* out = (float*)d_out;

    int total_threads = B_ROWS * NCHUNK;          // 131072
    dim3 block(256);
    dim3 grid(total_threads / 256);               // 512 blocks
    hipLaunchKernelGGL(pzcell_kernel, grid, block, 0, stream,
                       x, gain_ri, poles_ri, zeros_ri, out);
}

// Round 2
// 95.857 us; speedup vs baseline: 1.6879x; 1.6879x over previous
//
#include <hip/hip_runtime.h>

// PZCell exact chunked-scan biquad.
//   y_t = b0 x_t + b1 x_{t-1} + b2 x_{t-2} - a1 y_{t-1} - a2 y_{t-2}
// (pole_coeffs[0]==1 so den==1; real-state cast => only Re(coeffs) matter.)
//
// Decomposition per row (T=2048): 64 lanes x CHUNK=32 steps.
//  Phase 1: each lane runs its chunk from zero y-state (x predecessors are
//           known inputs, loaded exactly) keeping 32 outputs in VGPRs;
//           final y-state d_c = (y_31, y_30).
//  Phase 2: wave-wide Kogge-Stone scan of s_{c+1} = M s_c + d_c, M = A^32,
//           A = [[-a1,-a2],[1,0]]. Round matrices M^k by repeated squaring.
//  Phase 3: correction c_t = -a1 c_{t-1} - a2 c_{t-2} seeded with the
//           exclusive-scanned initial state, added to the register outputs.
// Exact up to fp reassociation -- no warmup approximation.

#define T_LEN   2048
#define B_ROWS  4096
#define CHUNK   32
#define LANES   64          // T_LEN / CHUNK
#define ROWS_PER_BLOCK 4    // 256 threads

__global__ __launch_bounds__(256, 4) void pzcell_scan_kernel(
    const float* __restrict__ x,
    const float* __restrict__ gain_ri,
    const float* __restrict__ poles_ri,
    const float* __restrict__ zeros_ri,
    float* __restrict__ out)
{
    // ---- coefficients (uniform) ----
    float gr = gain_ri[0], gi = gain_ri[1];
    float p1r = poles_ri[0];
    float p2r = poles_ri[2];
    float p1i = poles_ri[1], p2i = poles_ri[3];
    float z1r = zeros_ri[0], z1i = zeros_ri[1];
    float z2r = zeros_ri[2], z2i = zeros_ri[3];

    float a1 = -(p1r + p2r);              // Re(pole_coeffs[1])
    float a2 = p1r * p2r - p1i * p2i;     // Re(pole_coeffs[2])
    float zc1r = -(z1r + z2r), zc1i = -(z1i + z2i);
    float zc2r = z1r * z2r - z1i * z2i;
    float zc2i = z1r * z2i + z1i * z2r;
    float b0 = gr;
    float b1 = gr * zc1r - gi * zc1i;
    float b2 = gr * zc2r - gi * zc2i;

    int lane = threadIdx.x & 63;
    int wv   = threadIdx.x >> 6;
    int row  = blockIdx.x * ROWS_PER_BLOCK + wv;

    const float* xr = x + (size_t)row * T_LEN + lane * CHUNK;

    // x predecessors across chunk boundary (known inputs; exact)
    float xm1 = 0.f, xm2 = 0.f;
    if (lane > 0) { xm1 = xr[-1]; xm2 = xr[-2]; }

    // load the chunk's 32 inputs (8 independent float4s, all in flight)
    float4 xv[8];
#pragma unroll
    for (int i = 0; i < 8; ++i) xv[i] = ((const float4*)xr)[i];

    // ---- phase 1: zero-init recurrence, outputs stay in registers ----
    float y[CHUNK];
    float y1 = 0.f, y2 = 0.f;
#pragma unroll
    for (int i = 0; i < 8; ++i) {
        float xi, f, yt;
        xi = xv[i].x;
        f  = b0 * xi + b1 * xm1 + b2 * xm2;
        yt = f - a1 * y1 - a2 * y2;
        y[4 * i + 0] = yt; xm2 = xm1; xm1 = xi; y2 = y1; y1 = yt;

        xi = xv[i].y;
        f  = b0 * xi + b1 * xm1 + b2 * xm2;
        yt = f - a1 * y1 - a2 * y2;
        y[4 * i + 1] = yt; xm2 = xm1; xm1 = xi; y2 = y1; y1 = yt;

        xi = xv[i].z;
        f  = b0 * xi + b1 * xm1 + b2 * xm2;
        yt = f - a1 * y1 - a2 * y2;
        y[4 * i + 2] = yt; xm2 = xm1; xm1 = xi; y2 = y1; y1 = yt;

        xi = xv[i].w;
        f  = b0 * xi + b1 * xm1 + b2 * xm2;
        yt = f - a1 * y1 - a2 * y2;
        y[4 * i + 3] = yt; xm2 = xm1; xm1 = xi; y2 = y1; y1 = yt;
    }

    // ---- phase 2: M = A^32 via 5 squarings ----
    float m00 = -a1, m01 = -a2, m10 = 1.f, m11 = 0.f;
#pragma unroll
    for (int s = 0; s < 5; ++s) {
        float t00 = m00 * m00 + m01 * m10;
        float t01 = m00 * m01 + m01 * m11;
        float t10 = m10 * m00 + m11 * m10;
        float t11 = m10 * m01 + m11 * m11;
        m00 = t00; m01 = t01; m10 = t10; m11 = t11;
    }

    // inclusive Kogge-Stone scan of v_l = M v_{l-1} + d_l over 64 lanes
    float v1 = y1, v2 = y2;                 // d = (y_31, y_30)
    float p00 = m00, p01 = m01, p10 = m10, p11 = m11;
#pragma unroll
    for (int k = 1; k < 64; k <<= 1) {
        float u1 = __shfl_up(v1, (unsigned)k);
        float u2 = __shfl_up(v2, (unsigned)k);
        if (lane < k) { u1 = 0.f; u2 = 0.f; }
        v1 += p00 * u1 + p01 * u2;
        v2 += p10 * u1 + p11 * u2;
        float t00 = p00 * p00 + p01 * p10;  // square for next offset
        float t01 = p00 * p01 + p01 * p11;
        float t10 = p10 * p00 + p11 * p10;
        float t11 = p10 * p01 + p11 * p11;
        p00 = t00; p01 = t01; p10 = t10; p11 = t11;
    }

    // exclusive: this chunk's true initial y-state
    float s1 = __shfl_up(v1, 1);
    float s2 = __shfl_up(v2, 1);
    if (lane == 0) { s1 = 0.f; s2 = 0.f; }

    // ---- phase 3: homogeneous correction + store (128B/lane contiguous) ----
    float4* yo = (float4*)(out + (size_t)row * T_LEN + lane * CHUNK);
    float c1 = s1, c2 = s2;
#pragma unroll
    for (int i = 0; i < 8; ++i) {
        float4 o; float c;
        c = -a1 * c1 - a2 * c2; o.x = y[4 * i + 0] + c; c2 = c1; c1 = c;
        c = -a1 * c1 - a2 * c2; o.y = y[4 * i + 1] + c; c2 = c1; c1 = c;
        c = -a1 * c1 - a2 * c2; o.z = y[4 * i + 2] + c; c2 = c1; c1 = c;
        c = -a1 * c1 - a2 * c2; o.w = y[4 * i + 3] + c; c2 = c1; c1 = c;
        yo[i] = o;
    }
}

extern "C" void kernel_launch(void* const* d_in, const int* in_sizes, int n_in,
                              void* d_out, int out_size, void* d_ws, size_t ws_size,
                              hipStream_t stream) {
    const float* x        = (const float*)d_in[0];
    const float* gain_ri  = (const float*)d_in[1];
    const float* poles_ri = (const float*)d_in[2];
    const float* zeros_ri = (const float*)d_in[3];
    float* out = (float*)d_out;

    dim3 block(64 * ROWS_PER_BLOCK);                  // 256
    dim3 grid(B_ROWS / ROWS_PER_BLOCK);               // 1024 blocks, 4096 waves
    hipLaunchKernelGGL(pzcell_scan_kernel, grid, block, 0, stream,
                       x, gain_ri, poles_ri, zeros_ri, out);
}

// Round 8
// 86.324 us; speedup vs baseline: 1.8744x; 1.1104x over previous
//
#include <hip/hip_runtime.h>

// PZCell exact chunked-scan biquad, LDS-coalesced I/O.
//   y_t = b0 x_t + b1 x_{t-1} + b2 x_{t-2} - a1 y_{t-1} - a2 y_{t-2}
// One wave per row (T=2048): 64 lanes x CHUNK=32.
//  - Coalesced global float4 loads -> XOR-swizzled per-wave LDS -> per-lane
//    contiguous ds_read_b128 chunks (bank-balanced both orders).
//  - Phase 1: zero-state recurrence per lane, outputs in VGPRs.
//  - Phase 2: wave Kogge-Stone scan of the 2-dim y-state (M = A^32).
//  - Phase 3: homogeneous correction, write back through LDS, coalesced store.
// Exact up to fp reassociation.

#define T_LEN   2048
#define B_ROWS  4096
#define CHUNK   32
#define ROWS_PER_BLOCK 4    // 4 waves = 256 threads, 8KB LDS per wave

__global__ __launch_bounds__(256, 4) void pzcell_scan_kernel(
    const float* __restrict__ x,
    const float* __restrict__ gain_ri,
    const float* __restrict__ poles_ri,
    const float* __restrict__ zeros_ri,
    float* __restrict__ out)
{
    __shared__ float lds[ROWS_PER_BLOCK][T_LEN];   // 32 KiB

    // ---- coefficients (uniform) ----
    float gr = gain_ri[0], gi = gain_ri[1];
    float p1r = poles_ri[0];
    float p2r = poles_ri[2];
    float p1i = poles_ri[1], p2i = poles_ri[3];
    float z1r = zeros_ri[0], z1i = zeros_ri[1];
    float z2r = zeros_ri[2], z2i = zeros_ri[3];

    float a1 = -(p1r + p2r);              // Re(pole_coeffs[1])
    float a2 = p1r * p2r - p1i * p2i;     // Re(pole_coeffs[2])
    float zc1r = -(z1r + z2r), zc1i = -(z1i + z2i);
    float zc2r = z1r * z2r - z1i * z2i;
    float zc2i = z1r * z2i + z1i * z2r;
    float b0 = gr;
    float b1 = gr * zc1r - gi * zc1i;
    float b2 = gr * zc2r - gi * zc2i;

    int lane = threadIdx.x & 63;
    int wv   = threadIdx.x >> 6;
    int row  = blockIdx.x * ROWS_PER_BLOCK + wv;

    float4* l4 = (float4*)lds[wv];                 // 512 float4 slots per row

    // ---- coalesced load -> swizzled LDS ----
    const float4* xg4 = (const float4*)(x + (size_t)row * T_LEN);
    int swz_g = (lane >> 3) & 7;                   // ((g>>3)&7) for g=j*64+lane
#pragma unroll
    for (int j = 0; j < 8; ++j) {
        int g = j * 64 + lane;
        l4[g ^ swz_g] = xg4[g];
    }
    __syncthreads();

    // ---- per-lane chunk from LDS (chunk slot q=lane*8+k -> q^(lane&7)) ----
    float4 xv[8];
    int qbase = lane * 8, swz_c = lane & 7;
#pragma unroll
    for (int k = 0; k < 8; ++k) xv[k] = l4[(qbase + k) ^ swz_c];

    // cross-chunk x predecessors: previous lane's last two elements
    float xm1 = __shfl_up(xv[7].w, 1);
    float xm2 = __shfl_up(xv[7].z, 1);
    if (lane == 0) { xm1 = 0.f; xm2 = 0.f; }

    // ---- phase 1: zero-init recurrence, outputs stay in registers ----
    float y[CHUNK];
    float y1 = 0.f, y2 = 0.f;
#pragma unroll
    for (int i = 0; i < 8; ++i) {
        float xi, f, yt;
        xi = xv[i].x;
        f  = b0 * xi + b1 * xm1 + b2 * xm2;
        yt = f - a1 * y1 - a2 * y2;
        y[4 * i + 0] = yt; xm2 = xm1; xm1 = xi; y2 = y1; y1 = yt;

        xi = xv[i].y;
        f  = b0 * xi + b1 * xm1 + b2 * xm2;
        yt = f - a1 * y1 - a2 * y2;
        y[4 * i + 1] = yt; xm2 = xm1; xm1 = xi; y2 = y1; y1 = yt;

        xi = xv[i].z;
        f  = b0 * xi + b1 * xm1 + b2 * xm2;
        yt = f - a1 * y1 - a2 * y2;
        y[4 * i + 2] = yt; xm2 = xm1; xm1 = xi; y2 = y1; y1 = yt;

        xi = xv[i].w;
        f  = b0 * xi + b1 * xm1 + b2 * xm2;
        yt = f - a1 * y1 - a2 * y2;
        y[4 * i + 3] = yt; xm2 = xm1; xm1 = xi; y2 = y1; y1 = yt;
    }

    // ---- phase 2: M = A^32 via 5 squarings; Kogge-Stone over 64 lanes ----
    float m00 = -a1, m01 = -a2, m10 = 1.f, m11 = 0.f;
#pragma unroll
    for (int s = 0; s < 5; ++s) {
        float t00 = m00 * m00 + m01 * m10;
        float t01 = m00 * m01 + m01 * m11;
        float t10 = m10 * m00 + m11 * m10;
        float t11 = m10 * m01 + m11 * m11;
        m00 = t00; m01 = t01; m10 = t10; m11 = t11;
    }

    float v1 = y1, v2 = y2;                 // chunk-final state d = (y_31, y_30)
    float p00 = m00, p01 = m01, p10 = m10, p11 = m11;
#pragma unroll
    for (int k = 1; k < 64; k <<= 1) {
        float u1 = __shfl_up(v1, (unsigned)k);
        float u2 = __shfl_up(v2, (unsigned)k);
        if (lane < k) { u1 = 0.f; u2 = 0.f; }
        v1 += p00 * u1 + p01 * u2;
        v2 += p10 * u1 + p11 * u2;
        float t00 = p00 * p00 + p01 * p10;
        float t01 = p00 * p01 + p01 * p11;
        float t10 = p10 * p00 + p11 * p10;
        float t11 = p10 * p01 + p11 * p11;
        p00 = t00; p01 = t01; p10 = t10; p11 = t11;
    }

    float s1 = __shfl_up(v1, 1);            // exclusive: true initial y-state
    float s2 = __shfl_up(v2, 1);
    if (lane == 0) { s1 = 0.f; s2 = 0.f; }

    // ---- phase 3: correction, write y -> swizzled LDS ----
    __syncthreads();                        // x fully consumed; reuse buffer
    float c1 = s1, c2 = s2;
#pragma unroll
    for (int i = 0; i < 8; ++i) {
        float4 o; float c;
        c = -a1 * c1 - a2 * c2; o.x = y[4 * i + 0] + c; c2 = c1; c1 = c;
        c = -a1 * c1 - a2 * c2; o.y = y[4 * i + 1] + c; c2 = c1; c1 = c;
        c = -a1 * c1 - a2 * c2; o.z = y[4 * i + 2] + c; c2 = c1; c1 = c;
        c = -a1 * c1 - a2 * c2; o.w = y[4 * i + 3] + c; c2 = c1; c1 = c;
        l4[(qbase + i) ^ swz_c] = o;
    }
    __syncthreads();

    // ---- coalesced store ----
    float4* og4 = (float4*)(out + (size_t)row * T_LEN);
#pragma unroll
    for (int j = 0; j < 8; ++j) {
        int g = j * 64 + lane;
        og4[g] = l4[g ^ swz_g];
    }
}

extern "C" void kernel_launch(void* const* d_in, const int* in_sizes, int n_in,
                              void* d_out, int out_size, void* d_ws, size_t ws_size,
                              hipStream_t stream) {
    const float* x        = (const float*)d_in[0];
    const float* gain_ri  = (const float*)d_in[1];
    const float* poles_ri = (const float*)d_in[2];
    const float* zeros_ri = (const float*)d_in[3];
    float* out = (float*)d_out;

    dim3 block(64 * ROWS_PER_BLOCK);                  // 256
    dim3 grid(B_ROWS / ROWS_PER_BLOCK);               // 1024 blocks, 4096 waves
    hipLaunchKernelGGL(pzcell_scan_kernel, grid, block, 0, stream,
                       x, gain_ri, poles_ri, zeros_ri, out);
}